// Round 3
// baseline (2803.849 us; speedup 1.0000x reference)
//
#include <hip/hip_runtime.h>
#include <stdint.h>

#define BATCH 4096
#define IN_DIM 1024
#define HID 16384
#define KACT 64

__device__ __forceinline__ uint32_t fmap(float f) {
  uint32_t u = __float_as_uint(f);
  return (u & 0x80000000u) ? ~u : (u | 0x80000000u);  // order-preserving map
}

// ---------------------------------------------------------------------------
// Encoder GEMM replicating OpenBLAS sgemm accumulation bit-for-bit:
// per element, sequential fp32 FMA over k ascending, in Kc=384 panels;
// panel sums combined with single fp32 adds:
//   v = fl(fl(chain[0,384) + chain[384,768)) + chain[768,1024))
// 128x128 tile, 256 threads, 8x8 per-thread register tile, BK=16.
// ---------------------------------------------------------------------------
__global__ __launch_bounds__(256) void enc_gemm(const float* __restrict__ A,
                                                const float* __restrict__ Bw,
                                                float* __restrict__ C) {
  __shared__ float As[16][132];
  __shared__ float Bs[16][132];
  const int tid = threadIdx.x;
  const int bm = blockIdx.y;
  const int bn = blockIdx.x;
  const int m0 = (tid >> 4) << 3;
  const int n0 = (tid & 15) << 3;
  float tot[8][8] = {};
  float acc[8][8] = {};
  const float* Ablk = A + (size_t)bm * 128 * IN_DIM;
  const float* Bblk = Bw + (size_t)bn * 128 * IN_DIM;
  for (int k0 = 0; k0 < IN_DIM; k0 += 16) {
#pragma unroll
    for (int l = 0; l < 2; ++l) {
      int li = tid + l * 256;
      int row = li >> 2;
      int c4 = (li & 3) << 2;
      float4 va = *reinterpret_cast<const float4*>(Ablk + (size_t)row * IN_DIM + k0 + c4);
      As[c4 + 0][row] = va.x; As[c4 + 1][row] = va.y;
      As[c4 + 2][row] = va.z; As[c4 + 3][row] = va.w;
      float4 vb = *reinterpret_cast<const float4*>(Bblk + (size_t)row * IN_DIM + k0 + c4);
      Bs[c4 + 0][row] = vb.x; Bs[c4 + 1][row] = vb.y;
      Bs[c4 + 2][row] = vb.z; Bs[c4 + 3][row] = vb.w;
    }
    __syncthreads();
#pragma unroll
    for (int kk = 0; kk < 16; ++kk) {
      float a[8], b[8];
#pragma unroll
      for (int i = 0; i < 8; ++i) a[i] = As[kk][m0 + i];
#pragma unroll
      for (int j = 0; j < 8; ++j) b[j] = Bs[kk][n0 + j];
#pragma unroll
      for (int i = 0; i < 8; ++i)
#pragma unroll
        for (int j = 0; j < 8; ++j) acc[i][j] = fmaf(a[i], b[j], acc[i][j]);
    }
    __syncthreads();
    const int kend = k0 + 16;
    if (kend == 384 || kend == 768 || kend == IN_DIM) {  // panel boundary
#pragma unroll
      for (int i = 0; i < 8; ++i)
#pragma unroll
        for (int j = 0; j < 8; ++j) { tot[i][j] += acc[i][j]; acc[i][j] = 0.0f; }
    }
  }
  float* Cblk = C + (size_t)(bm * 128) * HID + bn * 128;
#pragma unroll
  for (int i = 0; i < 8; ++i) {
    float4 v0 = make_float4(tot[i][0], tot[i][1], tot[i][2], tot[i][3]);
    float4 v1 = make_float4(tot[i][4], tot[i][5], tot[i][6], tot[i][7]);
    *reinterpret_cast<float4*>(Cblk + (size_t)(m0 + i) * HID + n0) = v0;
    *reinterpret_cast<float4*>(Cblk + (size_t)(m0 + i) * HID + n0 + 4) = v1;
  }
}

// ---------------------------------------------------------------------------
// Exact top-64 per row on the fp32 values via 4-pass radix select.
// Ties at the boundary value: lowest index first (lax.top_k / stable argsort).
// Zeros non-kept entries in place; emits compact (idx,val) list.
// ---------------------------------------------------------------------------
__global__ __launch_bounds__(256) void topk_kernel(float* __restrict__ enc,
                                                   int* __restrict__ tk_idx,
                                                   float* __restrict__ tk_val) {
  const int b = blockIdx.x;
  const int tid = threadIdx.x;
  float* row = enc + (size_t)b * HID;

  uint32_t keys[64];
#pragma unroll
  for (int i = 0; i < 64; ++i) keys[i] = fmap(row[tid + (i << 8)]);

  __shared__ uint32_t hist[256];
  __shared__ uint32_t sfx[256];
  __shared__ uint32_t s_prefix, s_krem;
  __shared__ int eqidx[256];
  __shared__ uint32_t eqcnt;
  if (tid == 0) { s_prefix = 0u; s_krem = KACT; }

  for (int pass = 0; pass < 4; ++pass) {
    const int shift = 24 - pass * 8;
    hist[tid] = 0;
    __syncthreads();
    const uint32_t pm = pass ? (0xFFFFFFFFu << (shift + 8)) : 0u;
    const uint32_t prefix = s_prefix;
#pragma unroll
    for (int i = 0; i < 64; ++i)
      if ((keys[i] & pm) == prefix) atomicAdd(&hist[(keys[i] >> shift) & 255], 1u);
    __syncthreads();
    sfx[tid] = hist[tid];
    __syncthreads();
    for (int d = 1; d < 256; d <<= 1) {
      uint32_t add = (tid + d < 256) ? sfx[tid + d] : 0u;
      __syncthreads();
      sfx[tid] += add;
      __syncthreads();
    }
    const uint32_t krem = s_krem;
    __syncthreads();
    const uint32_t above = sfx[tid] - hist[tid];
    if (above < krem && sfx[tid] >= krem) {
      s_prefix = prefix | ((uint32_t)tid << shift);
      s_krem = krem - above;
    }
    __syncthreads();
  }

  const uint32_t T = s_prefix;       // key of the 64th-largest value
  const uint32_t take_eq = s_krem;   // how many equal-to-T to keep (low idx)

  if (tid == 0) eqcnt = 0;
  __syncthreads();
#pragma unroll
  for (int i = 0; i < 64; ++i)
    if (keys[i] == T) {
      uint32_t p = atomicAdd(&eqcnt, 1u);
      if (p < 256u) eqidx[p] = tid + (i << 8);
    }
  __syncthreads();
  if (tid == 0) {
    int n = (int)min(eqcnt, 256u);
    for (int a = 1; a < n; ++a) {
      int v = eqidx[a]; int c = a - 1;
      while (c >= 0 && eqidx[c] > v) { eqidx[c + 1] = eqidx[c]; --c; }
      eqidx[c + 1] = v;
    }
  }
  __syncthreads();

  uint64_t keepm = 0ull;
  uint32_t cnt = 0;
#pragma unroll
  for (int i = 0; i < 64; ++i) {
    const int idx = tid + (i << 8);
    const uint32_t u = keys[i];
    bool keep = (u > T);
    if (u == T) {
      for (uint32_t e = 0; e < take_eq; ++e)
        if (eqidx[e] == idx) { keep = true; break; }
    }
    if (keep) { keepm |= (1ull << i); ++cnt; }
  }
  sfx[tid] = cnt;
  __syncthreads();
  for (int d = 1; d < 256; d <<= 1) {
    uint32_t add = (tid >= d) ? sfx[tid - d] : 0u;
    __syncthreads();
    sfx[tid] += add;
    __syncthreads();
  }
  uint32_t pos = sfx[tid] - cnt;

#pragma unroll
  for (int i = 0; i < 64; ++i) {
    const int idx = tid + (i << 8);
    const uint32_t u = keys[i];
    const uint32_t sbits = (u & 0x80000000u) ? (u ^ 0x80000000u) : ~u;
    const float f = __uint_as_float(sbits);
    const bool keep = (keepm >> i) & 1ull;
    row[idx] = keep ? f : 0.0f;
    if (keep) {
      tk_idx[(size_t)b * KACT + pos] = idx;
      tk_val[(size_t)b * KACT + pos] = f;
      ++pos;
    }
  }
}

// ---------------------------------------------------------------------------
// W_dec [IN_DIM][HID] -> W_decT [HID][IN_DIM]
// ---------------------------------------------------------------------------
__global__ __launch_bounds__(256) void transpose_wdec(const float* __restrict__ Wd,
                                                      float* __restrict__ WdT) {
  __shared__ float t[32][33];
  const int tx = threadIdx.x & 31;
  const int ty = threadIdx.x >> 5;
  const int hb = blockIdx.x * 32;
  const int ib = blockIdx.y * 32;
#pragma unroll
  for (int r = ty; r < 32; r += 8)
    t[r][tx] = Wd[(size_t)(ib + r) * HID + hb + tx];
  __syncthreads();
#pragma unroll
  for (int r = ty; r < 32; r += 8)
    WdT[(size_t)(hb + r) * IN_DIM + ib + tx] = t[tx][r];
}

// ---------------------------------------------------------------------------
// Decoder: decoded[b,:] = sum_k val_k * WdT[idx_k, :]
// ---------------------------------------------------------------------------
__global__ __launch_bounds__(256) void decoder_t(const int* __restrict__ tk_idx,
                                                 const float* __restrict__ tk_val,
                                                 const float* __restrict__ WdT,
                                                 float* __restrict__ out) {
  const int b = blockIdx.x;
  const int tid = threadIdx.x;
  __shared__ int sidx[KACT];
  __shared__ float sval[KACT];
  if (tid < KACT) {
    sidx[tid] = tk_idx[(size_t)b * KACT + tid];
    sval[tid] = tk_val[(size_t)b * KACT + tid];
  }
  __syncthreads();
  float acc[4] = {0.f, 0.f, 0.f, 0.f};
  for (int k = 0; k < KACT; ++k) {
    const float* wrow = WdT + (size_t)sidx[k] * IN_DIM;
    const float v = sval[k];
#pragma unroll
    for (int j = 0; j < 4; ++j) acc[j] = fmaf(v, wrow[tid + j * 256], acc[j]);
  }
#pragma unroll
  for (int j = 0; j < 4; ++j) out[(size_t)b * IN_DIM + tid + j * 256] = acc[j];
}

__global__ __launch_bounds__(256) void decoder_g(const int* __restrict__ tk_idx,
                                                 const float* __restrict__ tk_val,
                                                 const float* __restrict__ Wd,
                                                 float* __restrict__ out) {
  const int b = blockIdx.x;
  const int tid = threadIdx.x;
  __shared__ int sidx[KACT];
  __shared__ float sval[KACT];
  if (tid < KACT) {
    sidx[tid] = tk_idx[(size_t)b * KACT + tid];
    sval[tid] = tk_val[(size_t)b * KACT + tid];
  }
  __syncthreads();
  float acc[4] = {0.f, 0.f, 0.f, 0.f};
  for (int k = 0; k < KACT; ++k) {
    const int h = sidx[k];
    const float v = sval[k];
#pragma unroll
    for (int j = 0; j < 4; ++j)
      acc[j] = fmaf(v, Wd[(size_t)(tid + j * 256) * HID + h], acc[j]);
  }
#pragma unroll
  for (int j = 0; j < 4; ++j) out[(size_t)b * IN_DIM + tid + j * 256] = acc[j];
}

// ---------------------------------------------------------------------------
extern "C" void kernel_launch(void* const* d_in, const int* in_sizes, int n_in,
                              void* d_out, int out_size, void* d_ws, size_t ws_size,
                              hipStream_t stream) {
  const float* x = (const float*)d_in[0];      // [BATCH, IN_DIM]
  const float* Wenc = (const float*)d_in[1];   // [HID, IN_DIM]
  const float* Wdec = (const float*)d_in[2];   // [IN_DIM, HID]
  float* out = (float*)d_out;
  float* decoded = out;                              // [BATCH, IN_DIM]
  float* sparse = out + (size_t)BATCH * IN_DIM;      // [BATCH, HID]

  int* tk_idx = (int*)d_ws;
  float* tk_val = (float*)((char*)d_ws + (size_t)BATCH * KACT * 4);
  float* WdT = (float*)((char*)d_ws + (size_t)BATCH * KACT * 8);
  const size_t need_t = (size_t)BATCH * KACT * 8 + (size_t)IN_DIM * HID * 4;
  const bool use_t = ws_size >= need_t;

  enc_gemm<<<dim3(HID / 128, BATCH / 128), 256, 0, stream>>>(x, Wenc, sparse);
  if (use_t)
    transpose_wdec<<<dim3(HID / 32, IN_DIM / 32), 256, 0, stream>>>(Wdec, WdT);
  topk_kernel<<<dim3(BATCH), 256, 0, stream>>>(sparse, tk_idx, tk_val);
  if (use_t)
    decoder_t<<<dim3(BATCH), 256, 0, stream>>>(tk_idx, tk_val, WdT, decoded);
  else
    decoder_g<<<dim3(BATCH), 256, 0, stream>>>(tk_idx, tk_val, Wdec, decoded);
}

// Round 4
// 1117.771 us; speedup vs baseline: 2.5084x; 2.5084x over previous
//
#include <hip/hip_runtime.h>
#include <stdint.h>

#define BATCH 4096
#define IN_DIM 1024
#define HID 16384
#define KACT 64
#define EPS2 4e-3f      // 2x bound on |v_mfma - v_np_chain| (worst ~8e-4)
#define CCAP 64

typedef short bf16x8 __attribute__((ext_vector_type(8)));
typedef float f32x4 __attribute__((ext_vector_type(4)));

__device__ __forceinline__ uint32_t fmap(float f) {
  uint32_t u = __float_as_uint(f);
  return (u & 0x80000000u) ? ~u : (u | 0x80000000u);
}
__device__ __forceinline__ float funmap(uint32_t k) {
  uint32_t u = (k & 0x80000000u) ? (k ^ 0x80000000u) : ~k;
  return __uint_as_float(u);
}
__device__ __forceinline__ uint16_t f2bf(float f) {
  uint32_t u = __float_as_uint(f);
  return (uint16_t)((u + 0x7FFFu + ((u >> 16) & 1u)) >> 16);
}
__device__ __forceinline__ void gload_lds16(const void* g, void* l) {
  __builtin_amdgcn_global_load_lds(
      (const __attribute__((address_space(1))) unsigned int*)g,
      (__attribute__((address_space(3))) unsigned int*)l, 16, 0, 0);
}

// ---------------------------------------------------------------------------
// Split-bf16 conversion: out[row][0:1024)=bf16(v), out[row][1024:2048)=bf16(v-hi)
// ---------------------------------------------------------------------------
__global__ __launch_bounds__(256) void convert_hilo(const float* __restrict__ in,
                                                    uint16_t* __restrict__ out,
                                                    int rows) {
  size_t total = (size_t)rows * IN_DIM;
  for (size_t i = (size_t)blockIdx.x * 256 + threadIdx.x; i < total;
       i += (size_t)gridDim.x * 256) {
    float v = in[i];
    uint16_t hb = f2bf(v);
    float hv = __uint_as_float((uint32_t)hb << 16);
    uint16_t lb = f2bf(v - hv);
    size_t row = i >> 10, col = i & 1023;
    out[row * 2048 + col] = hb;
    out[row * 2048 + 1024 + col] = lb;
  }
}

// ---------------------------------------------------------------------------
// bf16 MFMA GEMM: C[b,h] = sum over 3 panel-phases of A2[b]·B2[h]
// A2 [4096][2048] (hi|lo), B2 [16384][2048] (hi|lo); phases (hi,hi),(hi,lo),(lo,hi)
// 128x128 tile, BK=64, 4 waves, global_load_lds(16B) w/ pre-swizzled source,
// XOR-swizzled ds_read_b128 (conflict-free), XCD-aware block swizzle.
// ---------------------------------------------------------------------------
__global__ __launch_bounds__(256) void mfma_gemm(const uint16_t* __restrict__ A2,
                                                 const uint16_t* __restrict__ B2,
                                                 float* __restrict__ C) {
  __shared__ __attribute__((aligned(16))) char lds[32768];  // A: 0..16K, B: 16K..32K
  const int tid = threadIdx.x;
  const int lane = tid & 63;
  const int wave = tid >> 6;
  const int wr = wave >> 1, wc = wave & 1;

  int wg = blockIdx.x;
  wg = (wg & 7) * (4096 / 8) + (wg >> 3);  // XCD swizzle (4096 % 8 == 0)
  const int bn = wg & 127;
  const int bm = wg >> 7;

  const char* Abase = (const char*)(A2 + (size_t)(bm * 128) * 2048);
  const char* Bbase = (const char*)(B2 + (size_t)(bn * 128) * 2048);

  const int srow = lane >> 3;           // 0..7 within 8-row chunk
  const int scolb = (lane & 7) << 4;    // 0..112 byte col

  f32x4 acc[4][4] = {};

  for (int kt = 0; kt < 48; ++kt) {
    const int ks = kt & 15;
    const int acolB = ((kt >= 32) ? 2048 : 0) + ks * 128;                 // bytes
    const int bcolB = ((kt >= 16 && kt < 32) ? 2048 : 0) + ks * 128;

    __syncthreads();  // previous compute done before overwrite
#pragma unroll
    for (int j = 0; j < 4; ++j) {
      const int r0 = wave * 32 + j * 8;
      const int row = r0 + srow;
      const int swz = (row & 7) << 4;
      gload_lds16(Abase + (size_t)row * 4096 + acolB + (scolb ^ swz),
                  lds + r0 * 128);
      gload_lds16(Bbase + (size_t)row * 4096 + bcolB + (scolb ^ swz),
                  lds + 16384 + r0 * 128);
    }
    __syncthreads();  // compiler drains vmcnt(0) before barrier

#pragma unroll
    for (int ku = 0; ku < 2; ++ku) {
      bf16x8 af[4], bf_[4];
      const int kb = ku * 64 + ((lane >> 4) << 4);
#pragma unroll
      for (int m = 0; m < 4; ++m) {
        const int row = wr * 64 + m * 16 + (lane & 15);
        af[m] = *(const bf16x8*)(lds + row * 128 + (kb ^ ((row & 7) << 4)));
      }
#pragma unroll
      for (int n = 0; n < 4; ++n) {
        const int row = wc * 64 + n * 16 + (lane & 15);
        bf_[n] = *(const bf16x8*)(lds + 16384 + row * 128 + (kb ^ ((row & 7) << 4)));
      }
#pragma unroll
      for (int m = 0; m < 4; ++m)
#pragma unroll
        for (int n = 0; n < 4; ++n)
          acc[m][n] = __builtin_amdgcn_mfma_f32_16x16x32_bf16(af[m], bf_[n],
                                                              acc[m][n], 0, 0, 0);
    }
  }

  const int cr = (lane >> 4) * 4;
  const int cc = lane & 15;
#pragma unroll
  for (int m = 0; m < 4; ++m)
#pragma unroll
    for (int n = 0; n < 4; ++n)
#pragma unroll
      for (int i = 0; i < 4; ++i) {
        const int grow = bm * 128 + wr * 64 + m * 16 + cr + i;
        const int gcol = bn * 128 + wc * 64 + n * 16 + cc;
        C[(size_t)grow * HID + gcol] = acc[m][n][i];
      }
}

// ---------------------------------------------------------------------------
// K4: per-row radix-select T_approx; sure-in (v > T+EPS2) kept in place,
// zone [T-EPS2, T+EPS2] -> candidate list for exact recompute; rest zeroed.
// ---------------------------------------------------------------------------
__global__ __launch_bounds__(256) void select_kernel(float* __restrict__ enc,
                                                     int* __restrict__ cand_idx,
                                                     float* __restrict__ cand_aval,
                                                     int* __restrict__ cand_cnt,
                                                     int* __restrict__ cand_need) {
  const int b = blockIdx.x;
  const int tid = threadIdx.x;
  float* row = enc + (size_t)b * HID;

  float vals[64];
#pragma unroll
  for (int i = 0; i < 64; ++i) vals[i] = row[tid + (i << 8)];

  __shared__ uint32_t hist[256];
  __shared__ uint32_t sfx[256];
  __shared__ uint32_t s_prefix, s_krem;
  if (tid == 0) { s_prefix = 0u; s_krem = KACT; }

  for (int pass = 0; pass < 4; ++pass) {
    const int shift = 24 - pass * 8;
    hist[tid] = 0;
    __syncthreads();
    const uint32_t pm = pass ? (0xFFFFFFFFu << (shift + 8)) : 0u;
    const uint32_t prefix = s_prefix;
#pragma unroll
    for (int i = 0; i < 64; ++i) {
      const uint32_t k = fmap(vals[i]);
      if ((k & pm) == prefix) atomicAdd(&hist[(k >> shift) & 255], 1u);
    }
    __syncthreads();
    sfx[tid] = hist[tid];
    __syncthreads();
    for (int d = 1; d < 256; d <<= 1) {
      uint32_t add = (tid + d < 256) ? sfx[tid + d] : 0u;
      __syncthreads();
      sfx[tid] += add;
      __syncthreads();
    }
    const uint32_t krem = s_krem;
    __syncthreads();
    const uint32_t above = sfx[tid] - hist[tid];
    if (above < krem && sfx[tid] >= krem) {
      s_prefix = prefix | ((uint32_t)tid << shift);
      s_krem = krem - above;
    }
    __syncthreads();
  }

  const float T_a = funmap(s_prefix);
  const float hi_thr = T_a + EPS2;
  const float lo_thr = T_a - EPS2;

  __shared__ uint32_t s_nc, s_cs;
  if (tid == 0) { s_nc = 0u; s_cs = 0u; }
  __syncthreads();

  uint32_t cs = 0;
#pragma unroll
  for (int i = 0; i < 64; ++i) {
    const int idx = tid + (i << 8);
    const float v = vals[i];
    const bool sure = v > hi_thr;
    if (sure) ++cs;
    else if (v >= lo_thr) {
      uint32_t p = atomicAdd(&s_nc, 1u);
      if (p < CCAP) {
        cand_idx[(size_t)b * CCAP + p] = idx;
        cand_aval[(size_t)b * CCAP + p] = v;
      }
    }
    row[idx] = sure ? v : 0.0f;
  }
  if (cs) atomicAdd(&s_cs, cs);
  __syncthreads();
  if (tid == 0) {
    cand_cnt[b] = (int)min(s_nc, (uint32_t)CCAP);
    cand_need[b] = KACT - (int)s_cs;
  }
}

// ---------------------------------------------------------------------------
// K5: exact np-matching value for each boundary candidate: sequential fp32
// FMA chain over k ascending, Kc=384 panels (breaks at 384/768/1024) —
// bit-identical to the r3-proven scheme.
// ---------------------------------------------------------------------------
__global__ __launch_bounds__(64) void exact_kernel(const float* __restrict__ x,
                                                   const float* __restrict__ Wenc,
                                                   const int* __restrict__ cand_idx,
                                                   const int* __restrict__ cand_cnt,
                                                   float* __restrict__ cand_eval) {
  const int b = blockIdx.x;
  const int tid = threadIdx.x;
  __shared__ float xs[IN_DIM];
  for (int i = tid; i < IN_DIM; i += 64) xs[i] = x[(size_t)b * IN_DIM + i];
  __syncthreads();
  const int cnt = cand_cnt[b];
  if (tid < cnt) {
    const float* w = Wenc + (size_t)cand_idx[(size_t)b * CCAP + tid] * IN_DIM;
    float tot = 0.f, acc = 0.f;
    for (int k = 0; k < IN_DIM; ++k) {
      acc = fmaf(xs[k], w[k], acc);
      if (k == 383 || k == 767 || k == 1023) { tot += acc; acc = 0.f; }
    }
    cand_eval[(size_t)b * CCAP + tid] = tot;
  }
}

// ---------------------------------------------------------------------------
// K6: rank candidates by (exact val desc, idx asc), patch winners into sparse
// row, then compact (idx,val) list via prefix scan.
// ---------------------------------------------------------------------------
__global__ __launch_bounds__(256) void finalize_kernel(float* __restrict__ enc,
                                                       const int* __restrict__ cand_idx,
                                                       const float* __restrict__ cand_aval,
                                                       const float* __restrict__ cand_eval,
                                                       const int* __restrict__ cand_cnt,
                                                       const int* __restrict__ cand_need,
                                                       int* __restrict__ tk_idx,
                                                       float* __restrict__ tk_val) {
  const int b = blockIdx.x;
  const int tid = threadIdx.x;
  float* row = enc + (size_t)b * HID;
  const int cnt = cand_cnt[b];
  const int need = cand_need[b];

  if (tid < cnt && need > 0) {
    const float e = cand_eval[(size_t)b * CCAP + tid];
    const int myidx = cand_idx[(size_t)b * CCAP + tid];
    int rank = 0;
    for (int c = 0; c < cnt; ++c) {
      const float ec = cand_eval[(size_t)b * CCAP + c];
      const int ic = cand_idx[(size_t)b * CCAP + c];
      rank += (ec > e) || (ec == e && ic < myidx);
    }
    if (rank < need) row[myidx] = cand_aval[(size_t)b * CCAP + tid];
  }
  __syncthreads();

  __shared__ uint32_t sfx[256];
  float vals[64];
  uint64_t keepm = 0ull;
  uint32_t c2 = 0;
#pragma unroll
  for (int i = 0; i < 64; ++i) {
    vals[i] = row[tid + (i << 8)];
    if (vals[i] != 0.0f) { keepm |= (1ull << i); ++c2; }
  }
  sfx[tid] = c2;
  __syncthreads();
  for (int d = 1; d < 256; d <<= 1) {
    uint32_t add = (tid >= d) ? sfx[tid - d] : 0u;
    __syncthreads();
    sfx[tid] += add;
    __syncthreads();
  }
  uint32_t pos = sfx[tid] - c2;
#pragma unroll
  for (int i = 0; i < 64; ++i) {
    if ((keepm >> i) & 1ull) {
      if (pos < KACT) {
        tk_idx[(size_t)b * KACT + pos] = tid + (i << 8);
        tk_val[(size_t)b * KACT + pos] = vals[i];
      }
      ++pos;
    }
  }
}

// ---------------------------------------------------------------------------
// W_dec [IN_DIM][HID] -> W_decT [HID][IN_DIM]
// ---------------------------------------------------------------------------
__global__ __launch_bounds__(256) void transpose_wdec(const float* __restrict__ Wd,
                                                      float* __restrict__ WdT) {
  __shared__ float t[32][33];
  const int tx = threadIdx.x & 31;
  const int ty = threadIdx.x >> 5;
  const int hb = blockIdx.x * 32;
  const int ib = blockIdx.y * 32;
#pragma unroll
  for (int r = ty; r < 32; r += 8)
    t[r][tx] = Wd[(size_t)(ib + r) * HID + hb + tx];
  __syncthreads();
#pragma unroll
  for (int r = ty; r < 32; r += 8)
    WdT[(size_t)(hb + r) * IN_DIM + ib + tx] = t[tx][r];
}

__global__ __launch_bounds__(256) void decoder_t(const int* __restrict__ tk_idx,
                                                 const float* __restrict__ tk_val,
                                                 const float* __restrict__ WdT,
                                                 float* __restrict__ out) {
  const int b = blockIdx.x;
  const int tid = threadIdx.x;
  __shared__ int sidx[KACT];
  __shared__ float sval[KACT];
  if (tid < KACT) {
    sidx[tid] = tk_idx[(size_t)b * KACT + tid];
    sval[tid] = tk_val[(size_t)b * KACT + tid];
  }
  __syncthreads();
  float acc[4] = {0.f, 0.f, 0.f, 0.f};
  for (int k = 0; k < KACT; ++k) {
    const float* wrow = WdT + (size_t)sidx[k] * IN_DIM;
    const float v = sval[k];
#pragma unroll
    for (int j = 0; j < 4; ++j) acc[j] = fmaf(v, wrow[tid + j * 256], acc[j]);
  }
#pragma unroll
  for (int j = 0; j < 4; ++j) out[(size_t)b * IN_DIM + tid + j * 256] = acc[j];
}

__global__ __launch_bounds__(256) void decoder_g(const int* __restrict__ tk_idx,
                                                 const float* __restrict__ tk_val,
                                                 const float* __restrict__ Wd,
                                                 float* __restrict__ out) {
  const int b = blockIdx.x;
  const int tid = threadIdx.x;
  __shared__ int sidx[KACT];
  __shared__ float sval[KACT];
  if (tid < KACT) {
    sidx[tid] = tk_idx[(size_t)b * KACT + tid];
    sval[tid] = tk_val[(size_t)b * KACT + tid];
  }
  __syncthreads();
  float acc[4] = {0.f, 0.f, 0.f, 0.f};
  for (int k = 0; k < KACT; ++k) {
    const int h = sidx[k];
    const float v = sval[k];
#pragma unroll
    for (int j = 0; j < 4; ++j)
      acc[j] = fmaf(v, Wd[(size_t)(tid + j * 256) * HID + h], acc[j]);
  }
#pragma unroll
  for (int j = 0; j < 4; ++j) out[(size_t)b * IN_DIM + tid + j * 256] = acc[j];
}

// ---------------------------------------------------------------------------
// Fallback (r3-proven): fp32 vector GEMM + radix topk (used if ws too small)
// ---------------------------------------------------------------------------
__global__ __launch_bounds__(256) void enc_gemm(const float* __restrict__ A,
                                                const float* __restrict__ Bw,
                                                float* __restrict__ C) {
  __shared__ float As[16][132];
  __shared__ float Bs[16][132];
  const int tid = threadIdx.x;
  const int bm = blockIdx.y;
  const int bn = blockIdx.x;
  const int m0 = (tid >> 4) << 3;
  const int n0 = (tid & 15) << 3;
  float tot[8][8] = {};
  float acc[8][8] = {};
  const float* Ablk = A + (size_t)bm * 128 * IN_DIM;
  const float* Bblk = Bw + (size_t)bn * 128 * IN_DIM;
  for (int k0 = 0; k0 < IN_DIM; k0 += 16) {
#pragma unroll
    for (int l = 0; l < 2; ++l) {
      int li = tid + l * 256;
      int row = li >> 2;
      int c4 = (li & 3) << 2;
      float4 va = *reinterpret_cast<const float4*>(Ablk + (size_t)row * IN_DIM + k0 + c4);
      As[c4 + 0][row] = va.x; As[c4 + 1][row] = va.y;
      As[c4 + 2][row] = va.z; As[c4 + 3][row] = va.w;
      float4 vb = *reinterpret_cast<const float4*>(Bblk + (size_t)row * IN_DIM + k0 + c4);
      Bs[c4 + 0][row] = vb.x; Bs[c4 + 1][row] = vb.y;
      Bs[c4 + 2][row] = vb.z; Bs[c4 + 3][row] = vb.w;
    }
    __syncthreads();
#pragma unroll
    for (int kk = 0; kk < 16; ++kk) {
      float a[8], b[8];
#pragma unroll
      for (int i = 0; i < 8; ++i) a[i] = As[kk][m0 + i];
#pragma unroll
      for (int j = 0; j < 8; ++j) b[j] = Bs[kk][n0 + j];
#pragma unroll
      for (int i = 0; i < 8; ++i)
#pragma unroll
        for (int j = 0; j < 8; ++j) acc[i][j] = fmaf(a[i], b[j], acc[i][j]);
    }
    __syncthreads();
    const int kend = k0 + 16;
    if (kend == 384 || kend == 768 || kend == IN_DIM) {
#pragma unroll
      for (int i = 0; i < 8; ++i)
#pragma unroll
        for (int j = 0; j < 8; ++j) { tot[i][j] += acc[i][j]; acc[i][j] = 0.0f; }
    }
  }
  float* Cblk = C + (size_t)(bm * 128) * HID + bn * 128;
#pragma unroll
  for (int i = 0; i < 8; ++i) {
    float4 v0 = make_float4(tot[i][0], tot[i][1], tot[i][2], tot[i][3]);
    float4 v1 = make_float4(tot[i][4], tot[i][5], tot[i][6], tot[i][7]);
    *reinterpret_cast<float4*>(Cblk + (size_t)(m0 + i) * HID + n0) = v0;
    *reinterpret_cast<float4*>(Cblk + (size_t)(m0 + i) * HID + n0 + 4) = v1;
  }
}

__global__ __launch_bounds__(256) void topk_kernel(float* __restrict__ enc,
                                                   int* __restrict__ tk_idx,
                                                   float* __restrict__ tk_val) {
  const int b = blockIdx.x;
  const int tid = threadIdx.x;
  float* row = enc + (size_t)b * HID;
  uint32_t keys[64];
#pragma unroll
  for (int i = 0; i < 64; ++i) keys[i] = fmap(row[tid + (i << 8)]);
  __shared__ uint32_t hist[256];
  __shared__ uint32_t sfx[256];
  __shared__ uint32_t s_prefix, s_krem;
  __shared__ int eqidx[256];
  __shared__ uint32_t eqcnt;
  if (tid == 0) { s_prefix = 0u; s_krem = KACT; }
  for (int pass = 0; pass < 4; ++pass) {
    const int shift = 24 - pass * 8;
    hist[tid] = 0;
    __syncthreads();
    const uint32_t pm = pass ? (0xFFFFFFFFu << (shift + 8)) : 0u;
    const uint32_t prefix = s_prefix;
#pragma unroll
    for (int i = 0; i < 64; ++i)
      if ((keys[i] & pm) == prefix) atomicAdd(&hist[(keys[i] >> shift) & 255], 1u);
    __syncthreads();
    sfx[tid] = hist[tid];
    __syncthreads();
    for (int d = 1; d < 256; d <<= 1) {
      uint32_t add = (tid + d < 256) ? sfx[tid + d] : 0u;
      __syncthreads();
      sfx[tid] += add;
      __syncthreads();
    }
    const uint32_t krem = s_krem;
    __syncthreads();
    const uint32_t above = sfx[tid] - hist[tid];
    if (above < krem && sfx[tid] >= krem) {
      s_prefix = prefix | ((uint32_t)tid << shift);
      s_krem = krem - above;
    }
    __syncthreads();
  }
  const uint32_t T = s_prefix;
  const uint32_t take_eq = s_krem;
  if (tid == 0) eqcnt = 0;
  __syncthreads();
#pragma unroll
  for (int i = 0; i < 64; ++i)
    if (keys[i] == T) {
      uint32_t p = atomicAdd(&eqcnt, 1u);
      if (p < 256u) eqidx[p] = tid + (i << 8);
    }
  __syncthreads();
  if (tid == 0) {
    int n = (int)min(eqcnt, 256u);
    for (int a = 1; a < n; ++a) {
      int v = eqidx[a]; int c = a - 1;
      while (c >= 0 && eqidx[c] > v) { eqidx[c + 1] = eqidx[c]; --c; }
      eqidx[c + 1] = v;
    }
  }
  __syncthreads();
  uint64_t keepm = 0ull;
  uint32_t cnt = 0;
#pragma unroll
  for (int i = 0; i < 64; ++i) {
    const int idx = tid + (i << 8);
    const uint32_t u = keys[i];
    bool keep = (u > T);
    if (u == T) {
      for (uint32_t e = 0; e < take_eq; ++e)
        if (eqidx[e] == idx) { keep = true; break; }
    }
    if (keep) { keepm |= (1ull << i); ++cnt; }
  }
  sfx[tid] = cnt;
  __syncthreads();
  for (int d = 1; d < 256; d <<= 1) {
    uint32_t add = (tid >= d) ? sfx[tid - d] : 0u;
    __syncthreads();
    sfx[tid] += add;
    __syncthreads();
  }
  uint32_t pos = sfx[tid] - cnt;
#pragma unroll
  for (int i = 0; i < 64; ++i) {
    const int idx = tid + (i << 8);
    const uint32_t u = keys[i];
    const uint32_t sbits = (u & 0x80000000u) ? (u ^ 0x80000000u) : ~u;
    const float f = __uint_as_float(sbits);
    const bool keep = (keepm >> i) & 1ull;
    row[idx] = keep ? f : 0.0f;
    if (keep) {
      tk_idx[(size_t)b * KACT + pos] = idx;
      tk_val[(size_t)b * KACT + pos] = f;
      ++pos;
    }
  }
}

// ---------------------------------------------------------------------------
extern "C" void kernel_launch(void* const* d_in, const int* in_sizes, int n_in,
                              void* d_out, int out_size, void* d_ws, size_t ws_size,
                              hipStream_t stream) {
  const float* x = (const float*)d_in[0];
  const float* Wenc = (const float*)d_in[1];
  const float* Wdec = (const float*)d_in[2];
  float* out = (float*)d_out;
  float* decoded = out;
  float* sparse = out + (size_t)BATCH * IN_DIM;

  const size_t MB = 1024ull * 1024ull;
  char* ws = (char*)d_ws;
  int*   tk_idx    = (int*)(ws + 0 * MB);
  float* tk_val    = (float*)(ws + 1 * MB);
  int*   cand_idx  = (int*)(ws + 2 * MB);
  float* cand_aval = (float*)(ws + 3 * MB);
  float* cand_eval = (float*)(ws + 4 * MB);
  int*   cand_cnt  = (int*)(ws + 5 * MB);
  int*   cand_need = (int*)(ws + 5 * MB + 16384);
  uint16_t* A2     = (uint16_t*)(ws + 6 * MB);    // 16 MB
  uint16_t* B2     = (uint16_t*)(ws + 22 * MB);   // 64 MB
  float* WdT       = (float*)(ws + 86 * MB);      // 64 MB

  const size_t need_new_t = 150 * MB;
  const size_t need_new_g = 86 * MB;
  const size_t need_old_t = 68 * MB;

  if (ws_size >= need_new_g) {
    const bool use_t = ws_size >= need_new_t;
    convert_hilo<<<1024, 256, 0, stream>>>(x, A2, BATCH);
    convert_hilo<<<4096, 256, 0, stream>>>(Wenc, B2, HID);
    mfma_gemm<<<4096, 256, 0, stream>>>(A2, B2, sparse);
    if (use_t)
      transpose_wdec<<<dim3(HID / 32, IN_DIM / 32), 256, 0, stream>>>(Wdec, WdT);
    select_kernel<<<BATCH, 256, 0, stream>>>(sparse, cand_idx, cand_aval,
                                             cand_cnt, cand_need);
    exact_kernel<<<BATCH, 64, 0, stream>>>(x, Wenc, cand_idx, cand_cnt, cand_eval);
    finalize_kernel<<<BATCH, 256, 0, stream>>>(sparse, cand_idx, cand_aval,
                                               cand_eval, cand_cnt, cand_need,
                                               tk_idx, tk_val);
    if (use_t)
      decoder_t<<<BATCH, 256, 0, stream>>>(tk_idx, tk_val, WdT, decoded);
    else
      decoder_g<<<BATCH, 256, 0, stream>>>(tk_idx, tk_val, Wdec, decoded);
  } else {
    // r3-proven fallback
    float* WdT2 = (float*)(ws + 2 * MB);
    const bool use_t = ws_size >= need_old_t;
    enc_gemm<<<dim3(HID / 128, BATCH / 128), 256, 0, stream>>>(x, Wenc, sparse);
    if (use_t)
      transpose_wdec<<<dim3(HID / 32, IN_DIM / 32), 256, 0, stream>>>(Wdec, WdT2);
    topk_kernel<<<BATCH, 256, 0, stream>>>(sparse, tk_idx, tk_val);
    if (use_t)
      decoder_t<<<BATCH, 256, 0, stream>>>(tk_idx, tk_val, WdT2, decoded);
    else
      decoder_g<<<BATCH, 256, 0, stream>>>(tk_idx, tk_val, Wdec, decoded);
  }
}